// Round 4
// baseline (57714.331 us; speedup 1.0000x reference)
//
#include <hip/hip_runtime.h>
#include <math.h>

#define HD 512
#define NB 32
#define LS 2048
#define SYNC_OFF (65536 + 3 * HD * HD)  // float offset of sync area in ws

// Swizzled LDS h-tile: 16 rows; each row = 16 k-blocks of 32 floats, each
// k-block padded to 36 floats (144 B) so the stride-128B ks read pattern
// spreads across banks instead of a 16-way conflict.
#define HSTRIDE 576                      // floats per LDS h row (16*36)
// smem: hst0 | hst1 | xchg (2 sub-blocks x 128 floats)
#define SMEM_FLOATS (2 * 16 * HSTRIDE + 256)   // 18432 + 256 = 18688
#define SMEM_BYTES (SMEM_FLOATS * 4)           // 74752

typedef float f32x4 __attribute__((ext_vector_type(4)));

// ---------------------------------------------------------------------------
// Kernel 1 (unchanged, known-good): Xi = x @ Wi0 + bi0 into d_out's [B,L,H].
// ---------------------------------------------------------------------------
__global__ __launch_bounds__(256) void xi_gemm(const float* __restrict__ x,
                                               const float* __restrict__ Wi0,
                                               const float* __restrict__ bi0,
                                               float* __restrict__ out) {
  __shared__ float As[16][68];
  __shared__ float Bs[16][68];
  const int bn = blockIdx.x * 64;
  const int bm = blockIdx.y * 64;
  const int tid = threadIdx.x;
  const int tm = (tid & 15) * 4;
  const int tn = (tid >> 4) * 4;
  float acc[4][4] = {};
  for (int k0 = 0; k0 < HD; k0 += 16) {
    {
      const int r = tid >> 2, ks = (tid & 3) * 4;
      const float4 av = *(const float4*)(x + (size_t)(bm + r) * HD + k0 + ks);
      As[ks + 0][r] = av.x; As[ks + 1][r] = av.y;
      As[ks + 2][r] = av.z; As[ks + 3][r] = av.w;
      const int kk = tid >> 4, ns = (tid & 15) * 4;
      *(float4*)&Bs[kk][ns] = *(const float4*)(Wi0 + (size_t)(k0 + kk) * HD + bn + ns);
    }
    __syncthreads();
#pragma unroll
    for (int k = 0; k < 16; ++k) {
      const float4 a = *(const float4*)&As[k][tm];
      const float4 b = *(const float4*)&Bs[k][tn];
      acc[0][0] = fmaf(a.x, b.x, acc[0][0]); acc[0][1] = fmaf(a.x, b.y, acc[0][1]);
      acc[0][2] = fmaf(a.x, b.z, acc[0][2]); acc[0][3] = fmaf(a.x, b.w, acc[0][3]);
      acc[1][0] = fmaf(a.y, b.x, acc[1][0]); acc[1][1] = fmaf(a.y, b.y, acc[1][1]);
      acc[1][2] = fmaf(a.y, b.z, acc[1][2]); acc[1][3] = fmaf(a.y, b.w, acc[1][3]);
      acc[2][0] = fmaf(a.z, b.x, acc[2][0]); acc[2][1] = fmaf(a.z, b.y, acc[2][1]);
      acc[2][2] = fmaf(a.z, b.z, acc[2][2]); acc[2][3] = fmaf(a.z, b.w, acc[2][3]);
      acc[3][0] = fmaf(a.w, b.x, acc[3][0]); acc[3][1] = fmaf(a.w, b.y, acc[3][1]);
      acc[3][2] = fmaf(a.w, b.z, acc[3][2]); acc[3][3] = fmaf(a.w, b.w, acc[3][3]);
    }
    __syncthreads();
  }
  const float4 bias = *(const float4*)(bi0 + bn + tn);
#pragma unroll
  for (int i = 0; i < 4; ++i) {
    float4 v;
    v.x = acc[i][0] + bias.x; v.y = acc[i][1] + bias.y;
    v.z = acc[i][2] + bias.z; v.w = acc[i][3] + bias.w;
    *(float4*)(out + (size_t)(bm + tm + i) * HD + bn + tn) = v;
  }
}

// ---------------------------------------------------------------------------
// Kernel 2 (unchanged): WT[z][c][k] = W_z[k][c], z in {Wh0, Wi1, Wh1}.
// ---------------------------------------------------------------------------
__global__ void transpose_w(const float* __restrict__ Wh0,
                            const float* __restrict__ Wi1,
                            const float* __restrict__ Wh1,
                            float* __restrict__ WT) {
  const int k = blockIdx.y;
  const int c = (blockIdx.x << 8) + threadIdx.x;
  const int z = blockIdx.z;
  const float* src = (z == 0) ? Wh0 : (z == 1) ? Wi1 : Wh1;
  WT[(size_t)z * HD * HD + (size_t)c * HD + k] = src[(size_t)k * HD + c];
}

// ---------------------------------------------------------------------------
// Kernel 3 (unchanged): init h dbufs (parity 1 = h[-1]) + zero sync area
// (now 8 stamp lines: own/reader copies per layer per group).
// ---------------------------------------------------------------------------
__global__ void init_h(const float* __restrict__ h0, float* __restrict__ ws) {
  const int i = blockIdx.x * 256 + threadIdx.x;  // [0, 32768)
  const float v = h0[i];
  if (i < 16384) ws[16384 + i] = v;                   // layer 0, parity 1
  else           ws[32768 + 16384 + (i - 16384)] = v; // layer 1, parity 1
  if (blockIdx.x == 0) {
    unsigned* syncp = (unsigned*)(ws + SYNC_OFF);
    syncp[threadIdx.x] = 0;
  }
}

// ---------------------------------------------------------------------------
// swz: float4 index [0,2048) of an 8192-float h slice -> swizzled LDS float
// offset.
// ---------------------------------------------------------------------------
__device__ __forceinline__ int swz(int idx) {
  const int row = idx >> 7, f4 = idx & 127;
  return row * HSTRIDE + (f4 >> 3) * 36 + (f4 & 7) * 4;
}

// Coherent 16B load / store (sc1 = device-coherent point; proven pattern).
#define LDG_C(dst, p) \
  asm volatile("global_load_dwordx4 %0, %1, off sc1" : "=v"(dst) : "v"(p))
#define STG_C(p, v) \
  asm volatile("global_store_dwordx4 %0, %1, off sc1" :: "v"(p), "v"(v) : "memory")

// ---------------------------------------------------------------------------
// Round-2-proven wait: wave0 polls (lanes 0-31 line a, lanes 32-63 line b),
// then barrier broadcasts. With the own/reader line split each stamp line
// has exactly 32 wave-pollers (round 2 had 64; round 3's all-wave polling
// had 512 and regressed — coherent-point line serialization).
// ---------------------------------------------------------------------------
__device__ __forceinline__ void stamp_wait(const unsigned* a, int ta,
                                           const unsigned* b, int tb) {
  if (threadIdx.x < 64) {
    const int l = threadIdx.x;
    const unsigned* p = (l < 32) ? (a + l) : (b + (l - 32));
    const int tg = (l < 32) ? ta : tb;
    for (;;) {
      const int sv = (int)__hip_atomic_load(p, __ATOMIC_RELAXED,
                                            __HIP_MEMORY_SCOPE_AGENT);
      if (__all(sv >= tg)) break;
      __builtin_amdgcn_s_sleep(1);
    }
  }
  __syncthreads();
}

// ---------------------------------------------------------------------------
// Kernel 4: persistent recurrence, 128 blocks x 512 threads.
// Round-4 changes vs the passing round-2 kernel:
//  - __launch_bounds__(512, 1): lifts the 128-VGPR cap that forced the
//    compiler to REMATERIALIZE the w[4][8] loads inside the t-loop
//    (observed VGPR_Count 104 < 128 needed for w alone) — i.e. every step
//    re-streamed ~256KB/block of weights from L1/L2. Weights now live in
//    registers across all 2048 steps.
//  - split stamp lines (own vs reader) -> 32 pollers/line.
//  - L0: butterfly reduce + float4 sc1 h-stores (round-3 parts, sound).
//  - L1: butterfly over ks + tiny LDS m-exchange replaces the 128x36 part
//    buffer round trip; float4 h1/out stores.
// Stamp semantics (value t+1 <=> block finished step t, h stores drained):
//  L0 step t: needs L0own >= t (h0[t-1] ready), L1rd >= t-1 (h0[t-2] free).
//  L1 step t: needs L0rd >= t+1 (h0[t] ready), L1own >= t (h1[t-1] ready,
//             h1 buffer free).
//  L1 writes out[b,t,:] only after L0rd >= t+1, i.e. after L0 consumed
//  xi[t] — the Xi-prefetch hazard argument is unchanged.
// ---------------------------------------------------------------------------
__global__ __launch_bounds__(512, 1) void rnn_persist(
    const float* __restrict__ WT,
    const float* __restrict__ bh0,
    const float* __restrict__ bi1,
    const float* __restrict__ bh1,
    float* __restrict__ outbuf,
    float* __restrict__ ws) {
  extern __shared__ float smem[];

  const int tid = threadIdx.x;
  const int bid = blockIdx.x;
  const int g = bid & 1;
  const int layer = (bid >> 1) & 1;
  const int cb2 = bid >> 2;          // [0,32)
  const int sb = tid >> 8;           // sub-block 0/1
  const int st = tid & 255;
  const int col0 = (cb2 * 2 + sb) * 8;
  const int bbase = g * 16;

  float* hst0 = smem;
  float* hst1 = smem + 16 * HSTRIDE;
  float* xchg = smem + 2 * 16 * HSTRIDE + sb * 128;

  float* h0b = ws;
  float* h1b = ws + 32768;
  unsigned* syncp = (unsigned*)(ws + SYNC_OFF);
  unsigned* L0own = syncp + g * 32;
  unsigned* L0rd  = syncp + 64 + g * 32;
  unsigned* L1own = syncp + 128 + g * 32;
  unsigned* L1rd  = syncp + 192 + g * 32;
  const size_t OUT0 = (size_t)NB * LS * HD;

  if (layer == 0) {
    const int cg = st & 1;                 // 2 col-groups of 4
    const int ks = (st >> 1) & 15;         // 16 k-slices of 32
    const int kb = ks * 32;
    const int bg = st >> 5;                // 8 b-groups of 2
    const bool act = (ks == 0);            // lanes {0,1,32,33} of each wave
    const int fb2 = bbase + bg * 2;
    float4 w[4][8];                        // 128 VGPRs — now register-resident
#pragma unroll
    for (int ci = 0; ci < 4; ++ci)
#pragma unroll
      for (int kk = 0; kk < 8; ++kk)
        w[ci][kk] = *(const float4*)(WT + (size_t)(col0 + cg * 4 + ci) * HD + kb + kk * 4);
    const float4 bias4 = *(const float4*)(bh0 + col0 + cg * 4);

    for (int t = 0; t < LS; ++t) {
      // Xi prefetch (plain cached) by act lanes; hazard-free per stamp order.
      f32x4 xi0 = {0.f, 0.f, 0.f, 0.f}, xi1 = {0.f, 0.f, 0.f, 0.f};
      if (act) {
        xi0 = *(const f32x4*)(outbuf + ((size_t)(fb2 + 0) * LS + t) * HD + col0 + cg * 4);
        xi1 = *(const f32x4*)(outbuf + ((size_t)(fb2 + 1) * LS + t) * HD + col0 + cg * 4);
      }

      stamp_wait(L0own, t, L1rd, t - 1);

      {  // stage h0[t-1] -> hst0 (coalesced 16B sc1 loads, swizzled LDS)
        const float* src = h0b + ((t + 1) & 1) * 16384 + bbase * HD;
        f32x4 a, b, c, d;
        LDG_C(a, src + ((0 * 512 + tid) << 2));
        LDG_C(b, src + ((1 * 512 + tid) << 2));
        LDG_C(c, src + ((2 * 512 + tid) << 2));
        LDG_C(d, src + ((3 * 512 + tid) << 2));
        asm volatile("s_waitcnt vmcnt(0)" ::: "memory");
        *(f32x4*)&hst0[swz(0 * 512 + tid)] = a;
        *(f32x4*)&hst0[swz(1 * 512 + tid)] = b;
        *(f32x4*)&hst0[swz(2 * 512 + tid)] = c;
        *(f32x4*)&hst0[swz(3 * 512 + tid)] = d;
      }
      __syncthreads();

      const float* rA = hst0 + (bg * 2) * HSTRIDE + ks * 36;
      const float* rB = rA + HSTRIDE;
      float acc[4][2] = {};
#pragma unroll
      for (int kk = 0; kk < 8; ++kk) {
        const float4 a4 = *(const float4*)(rA + kk * 4);
        const float4 b4 = *(const float4*)(rB + kk * 4);
#pragma unroll
        for (int ci = 0; ci < 4; ++ci) {
          const float4 wv = w[ci][kk];
          acc[ci][0] = fmaf(wv.x, a4.x, acc[ci][0]);
          acc[ci][0] = fmaf(wv.y, a4.y, acc[ci][0]);
          acc[ci][0] = fmaf(wv.z, a4.z, acc[ci][0]);
          acc[ci][0] = fmaf(wv.w, a4.w, acc[ci][0]);
          acc[ci][1] = fmaf(wv.x, b4.x, acc[ci][1]);
          acc[ci][1] = fmaf(wv.y, b4.y, acc[ci][1]);
          acc[ci][1] = fmaf(wv.z, b4.z, acc[ci][1]);
          acc[ci][1] = fmaf(wv.w, b4.w, acc[ci][1]);
        }
      }
      // Butterfly sum over ks (lane bits 1-4, intra-wave).
#pragma unroll
      for (int mask = 2; mask <= 16; mask <<= 1)
#pragma unroll
        for (int ci = 0; ci < 4; ++ci) {
          acc[ci][0] += __shfl_xor(acc[ci][0], mask, 64);
          acc[ci][1] += __shfl_xor(acc[ci][1], mask, 64);
        }

      if (act) {
        f32x4 h0v, h1v;
        h0v.x = tanhf(acc[0][0] + xi0.x + bias4.x);
        h0v.y = tanhf(acc[1][0] + xi0.y + bias4.y);
        h0v.z = tanhf(acc[2][0] + xi0.z + bias4.z);
        h0v.w = tanhf(acc[3][0] + xi0.w + bias4.w);
        h1v.x = tanhf(acc[0][1] + xi1.x + bias4.x);
        h1v.y = tanhf(acc[1][1] + xi1.y + bias4.y);
        h1v.z = tanhf(acc[2][1] + xi1.z + bias4.z);
        h1v.w = tanhf(acc[3][1] + xi1.w + bias4.w);
        float* dst = h0b + (t & 1) * 16384;
        STG_C(dst + (size_t)(fb2 + 0) * HD + col0 + cg * 4, h0v);
        STG_C(dst + (size_t)(fb2 + 1) * HD + col0 + cg * 4, h1v);
        if (t == LS - 1) {  // h_final L0
          *(f32x4*)(outbuf + OUT0 + (size_t)(fb2 + 0) * HD + col0 + cg * 4) = h0v;
          *(f32x4*)(outbuf + OUT0 + (size_t)(fb2 + 1) * HD + col0 + cg * 4) = h1v;
        }
      }
      // Drain inline-asm sc1 stores (invisible to compiler waitcnt tracking),
      // barrier, then publish both stamp copies.
      asm volatile("s_waitcnt vmcnt(0)" ::: "memory");
      __syncthreads();
      if (tid == 0) {
        __hip_atomic_store(L0own + cb2, (unsigned)(t + 1),
                           __ATOMIC_RELAXED, __HIP_MEMORY_SCOPE_AGENT);
        __hip_atomic_store(L0rd + cb2, (unsigned)(t + 1),
                           __ATOMIC_RELAXED, __HIP_MEMORY_SCOPE_AGENT);
      }
    }
  } else {
    const int m = st >> 7;                 // 0 = Wi1 (reads h0), 1 = Wh1 (reads h1)
    const int r = st & 127;
    const int cg = r & 1;
    const int ks = (r >> 1) & 15;
    const int kb = ks * 32;
    const int bg = r >> 5;                 // 4 b-groups of 4
    const bool act = (ks == 0);            // lanes {0,1,32,33} of each wave
    const int slot = bg * 2 + cg;          // [0,8) per m per sub-block
    float4 w[4][8];                        // register-resident
    const float* Wm = WT + (size_t)(1 + m) * HD * HD;
#pragma unroll
    for (int ci = 0; ci < 4; ++ci)
#pragma unroll
      for (int kk = 0; kk < 8; ++kk)
        w[ci][kk] = *(const float4*)(Wm + (size_t)(col0 + cg * 4 + ci) * HD + kb + kk * 4);
    float4 bias4;
    {
      const float4 b1 = *(const float4*)(bi1 + col0 + cg * 4);
      const float4 b2 = *(const float4*)(bh1 + col0 + cg * 4);
      bias4.x = b1.x + b2.x; bias4.y = b1.y + b2.y;
      bias4.z = b1.z + b2.z; bias4.w = b1.w + b2.w;
    }

    for (int t = 0; t < LS; ++t) {
      stamp_wait(L0rd, t + 1, L1own, t);

      {  // stage h0[t] -> hst0 and h1[t-1] -> hst1
        const float* s0 = h0b + (t & 1) * 16384 + bbase * HD;
        const float* s1 = h1b + ((t + 1) & 1) * 16384 + bbase * HD;
        f32x4 a, b, c, d, e, f, g2, h;
        LDG_C(a, s0 + ((0 * 512 + tid) << 2));
        LDG_C(b, s0 + ((1 * 512 + tid) << 2));
        LDG_C(c, s0 + ((2 * 512 + tid) << 2));
        LDG_C(d, s0 + ((3 * 512 + tid) << 2));
        LDG_C(e, s1 + ((0 * 512 + tid) << 2));
        LDG_C(f, s1 + ((1 * 512 + tid) << 2));
        LDG_C(g2, s1 + ((2 * 512 + tid) << 2));
        LDG_C(h, s1 + ((3 * 512 + tid) << 2));
        asm volatile("s_waitcnt vmcnt(0)" ::: "memory");
        *(f32x4*)&hst0[swz(0 * 512 + tid)] = a;
        *(f32x4*)&hst0[swz(1 * 512 + tid)] = b;
        *(f32x4*)&hst0[swz(2 * 512 + tid)] = c;
        *(f32x4*)&hst0[swz(3 * 512 + tid)] = d;
        *(f32x4*)&hst1[swz(0 * 512 + tid)] = e;
        *(f32x4*)&hst1[swz(1 * 512 + tid)] = f;
        *(f32x4*)&hst1[swz(2 * 512 + tid)] = g2;
        *(f32x4*)&hst1[swz(3 * 512 + tid)] = h;
      }
      __syncthreads();

      const float* hbase = (m == 0) ? hst0 : hst1;
      float acc[4][4] = {};
#pragma unroll
      for (int bj = 0; bj < 4; ++bj) {
        const float* hr = hbase + (bg * 4 + bj) * HSTRIDE + ks * 36;
#pragma unroll
        for (int kk = 0; kk < 8; ++kk) {
          const float4 h4 = *(const float4*)(hr + kk * 4);
#pragma unroll
          for (int ci = 0; ci < 4; ++ci) {
            const float4 wv = w[ci][kk];
            acc[ci][bj] = fmaf(wv.x, h4.x, acc[ci][bj]);
            acc[ci][bj] = fmaf(wv.y, h4.y, acc[ci][bj]);
            acc[ci][bj] = fmaf(wv.z, h4.z, acc[ci][bj]);
            acc[ci][bj] = fmaf(wv.w, h4.w, acc[ci][bj]);
          }
        }
      }
      // Butterfly over ks (lane bits 1-4, intra-wave); then m=1 hands its
      // sums to m=0 through an 8-slot LDS exchange (replaces the 128x36
      // part buffer + full-block reduce round trip).
#pragma unroll
      for (int mask = 2; mask <= 16; mask <<= 1)
#pragma unroll
        for (int ci = 0; ci < 4; ++ci)
#pragma unroll
          for (int bj = 0; bj < 4; ++bj)
            acc[ci][bj] += __shfl_xor(acc[ci][bj], mask, 64);

      if (m == 1 && act) {
        float* xc = xchg + slot * 16;
#pragma unroll
        for (int ci = 0; ci < 4; ++ci) {
          f32x4 v;
          v.x = acc[ci][0]; v.y = acc[ci][1];
          v.z = acc[ci][2]; v.w = acc[ci][3];
          *(f32x4*)&xc[ci * 4] = v;
        }
      }
      __syncthreads();
      if (m == 0 && act) {
        const float* xc = xchg + slot * 16;
#pragma unroll
        for (int bj = 0; bj < 4; ++bj) {
          f32x4 hv;
          hv.x = tanhf(acc[0][bj] + xc[0 * 4 + bj] + bias4.x);
          hv.y = tanhf(acc[1][bj] + xc[1 * 4 + bj] + bias4.y);
          hv.z = tanhf(acc[2][bj] + xc[2 * 4 + bj] + bias4.z);
          hv.w = tanhf(acc[3][bj] + xc[3 * 4 + bj] + bias4.w);
          const int b = bbase + bg * 4 + bj;
          STG_C(h1b + (t & 1) * 16384 + (size_t)b * HD + col0 + cg * 4, hv);
          *(f32x4*)(outbuf + ((size_t)b * LS + t) * HD + col0 + cg * 4) = hv;
          if (t == LS - 1)
            *(f32x4*)(outbuf + OUT0 + NB * HD + (size_t)b * HD + col0 + cg * 4) = hv;
        }
      }
      asm volatile("s_waitcnt vmcnt(0)" ::: "memory");
      __syncthreads();
      if (tid == 0) {
        __hip_atomic_store(L1own + cb2, (unsigned)(t + 1),
                           __ATOMIC_RELAXED, __HIP_MEMORY_SCOPE_AGENT);
        __hip_atomic_store(L1rd + cb2, (unsigned)(t + 1),
                           __ATOMIC_RELAXED, __HIP_MEMORY_SCOPE_AGENT);
      }
    }
  }
}

// ---------------------------------------------------------------------------
// ws layout (floats): [0,65536) h dbufs; [65536,65536+786432) WT;
// [SYNC_OFF, SYNC_OFF+256) stamps: 8 lines (L0own/L0rd/L1own/L1rd x 2 g).
// ---------------------------------------------------------------------------
extern "C" void kernel_launch(void* const* d_in, const int* in_sizes, int n_in,
                              void* d_out, int out_size, void* d_ws, size_t ws_size,
                              hipStream_t stream) {
  const float* x  = (const float*)d_in[0];
  const float* h0 = (const float*)d_in[1];
  const float* Wi = (const float*)d_in[2];
  const float* bi = (const float*)d_in[3];
  const float* Wh = (const float*)d_in[4];
  const float* bh = (const float*)d_in[5];
  float* out = (float*)d_out;
  float* ws  = (float*)d_ws;

  const float* Wi0 = Wi;
  const float* Wi1 = Wi + (size_t)HD * HD;
  const float* bi0 = bi;
  const float* bi1 = bi + HD;
  const float* Wh0 = Wh;
  const float* Wh1 = Wh + (size_t)HD * HD;
  const float* bh0 = bh;
  const float* bh1 = bh + HD;

  const float* WT = ws + 65536;

  static int attr_set = 0;
  if (!attr_set) {
    hipFuncSetAttribute((const void*)rnn_persist,
                        hipFuncAttributeMaxDynamicSharedMemorySize, SMEM_BYTES);
    attr_set = 1;
  }

  xi_gemm<<<dim3(8, 1024), 256, 0, stream>>>(x, Wi0, bi0, out);
  transpose_w<<<dim3(2, 512, 3), 256, 0, stream>>>(Wh0, Wi1, Wh1, ws + 65536);
  init_h<<<128, 256, 0, stream>>>(h0, ws);

  void* kargs[] = {(void*)&WT, (void*)&bh0, (void*)&bi1, (void*)&bh1,
                   (void*)&out, (void*)&ws};
  hipLaunchCooperativeKernel((const void*)rnn_persist, dim3(128), dim3(512),
                             kargs, SMEM_BYTES, stream);
}

// Round 6
// 9718.066 us; speedup vs baseline: 5.9389x; 5.9389x over previous
//
#include <hip/hip_runtime.h>
#include <math.h>

#define HD 512
#define NB 32
#define LS 2048
#define SYNC_OFF (65536 + 3 * HD * HD)  // float offset of sync area in ws

// LDS layouts.
// h tile: 16 rows x (16 k-blocks of 32 floats padded to 36) = 576 floats/row.
// weight tile: 16 cols x (16 k-blocks padded to 36) with col stride 580
// (576+4 stagger so cg pairs land 16 banks apart; ks vs ks+8 is 2-way = free).
#define HROW 576
#define WROW 580
#define HT_F (16 * HROW)                 // 9216 floats = 36 KB
#define WT_F (16 * WROW)                 // 9280 floats = 36.25 KB
#define PART_F 4608                      // 128*36 partial floats per sub-block
#define SMEM_FLOATS (2 * HT_F + 2 * WT_F)  // 36992
#define SMEM_BYTES (SMEM_FLOATS * 4)       // 147968 (< 160 KiB)

typedef float f32x4 __attribute__((ext_vector_type(4)));

// ---------------------------------------------------------------------------
// Kernel 1 (unchanged, known-good): Xi = x @ Wi0 + bi0 into d_out's [B,L,H].
// ---------------------------------------------------------------------------
__global__ __launch_bounds__(256) void xi_gemm(const float* __restrict__ x,
                                               const float* __restrict__ Wi0,
                                               const float* __restrict__ bi0,
                                               float* __restrict__ out) {
  __shared__ float As[16][68];
  __shared__ float Bs[16][68];
  const int bn = blockIdx.x * 64;
  const int bm = blockIdx.y * 64;
  const int tid = threadIdx.x;
  const int tm = (tid & 15) * 4;
  const int tn = (tid >> 4) * 4;
  float acc[4][4] = {};
  for (int k0 = 0; k0 < HD; k0 += 16) {
    {
      const int r = tid >> 2, ks = (tid & 3) * 4;
      const float4 av = *(const float4*)(x + (size_t)(bm + r) * HD + k0 + ks);
      As[ks + 0][r] = av.x; As[ks + 1][r] = av.y;
      As[ks + 2][r] = av.z; As[ks + 3][r] = av.w;
      const int kk = tid >> 4, ns = (tid & 15) * 4;
      *(float4*)&Bs[kk][ns] = *(const float4*)(Wi0 + (size_t)(k0 + kk) * HD + bn + ns);
    }
    __syncthreads();
#pragma unroll
    for (int k = 0; k < 16; ++k) {
      const float4 a = *(const float4*)&As[k][tm];
      const float4 b = *(const float4*)&Bs[k][tn];
      acc[0][0] = fmaf(a.x, b.x, acc[0][0]); acc[0][1] = fmaf(a.x, b.y, acc[0][1]);
      acc[0][2] = fmaf(a.x, b.z, acc[0][2]); acc[0][3] = fmaf(a.x, b.w, acc[0][3]);
      acc[1][0] = fmaf(a.y, b.x, acc[1][0]); acc[1][1] = fmaf(a.y, b.y, acc[1][1]);
      acc[1][2] = fmaf(a.y, b.z, acc[1][2]); acc[1][3] = fmaf(a.y, b.w, acc[1][3]);
      acc[2][0] = fmaf(a.z, b.x, acc[2][0]); acc[2][1] = fmaf(a.z, b.y, acc[2][1]);
      acc[2][2] = fmaf(a.z, b.z, acc[2][2]); acc[2][3] = fmaf(a.z, b.w, acc[2][3]);
      acc[3][0] = fmaf(a.w, b.x, acc[3][0]); acc[3][1] = fmaf(a.w, b.y, acc[3][1]);
      acc[3][2] = fmaf(a.w, b.z, acc[3][2]); acc[3][3] = fmaf(a.w, b.w, acc[3][3]);
    }
    __syncthreads();
  }
  const float4 bias = *(const float4*)(bi0 + bn + tn);
#pragma unroll
  for (int i = 0; i < 4; ++i) {
    float4 v;
    v.x = acc[i][0] + bias.x; v.y = acc[i][1] + bias.y;
    v.z = acc[i][2] + bias.z; v.w = acc[i][3] + bias.w;
    *(float4*)(out + (size_t)(bm + tm + i) * HD + bn + tn) = v;
  }
}

// ---------------------------------------------------------------------------
// Kernel 2 (unchanged): WT[z][c][k] = W_z[k][c], z in {Wh0, Wi1, Wh1}.
// ---------------------------------------------------------------------------
__global__ void transpose_w(const float* __restrict__ Wh0,
                            const float* __restrict__ Wi1,
                            const float* __restrict__ Wh1,
                            float* __restrict__ WT) {
  const int k = blockIdx.y;
  const int c = (blockIdx.x << 8) + threadIdx.x;
  const int z = blockIdx.z;
  const float* src = (z == 0) ? Wh0 : (z == 1) ? Wi1 : Wh1;
  WT[(size_t)z * HD * HD + (size_t)c * HD + k] = src[(size_t)k * HD + c];
}

// ---------------------------------------------------------------------------
// Kernel 3 (unchanged): init h dbufs (parity 1 = h[-1]) + zero sync area.
// ---------------------------------------------------------------------------
__global__ void init_h(const float* __restrict__ h0, float* __restrict__ ws) {
  const int i = blockIdx.x * 256 + threadIdx.x;  // [0, 32768)
  const float v = h0[i];
  if (i < 16384) ws[16384 + i] = v;                   // layer 0, parity 1
  else           ws[32768 + 16384 + (i - 16384)] = v; // layer 1, parity 1
  if (blockIdx.x == 0) {
    unsigned* syncp = (unsigned*)(ws + SYNC_OFF);
    syncp[threadIdx.x] = 0;
  }
}

// ---------------------------------------------------------------------------
// swz: float4 index [0,2048) of an 8192-float h slice -> swizzled LDS float
// offset (HROW stride). wswz: same for weight tiles (WROW stride).
// ---------------------------------------------------------------------------
__device__ __forceinline__ int swz(int idx) {
  const int row = idx >> 7, f4 = idx & 127;
  return row * HROW + (f4 >> 3) * 36 + (f4 & 7) * 4;
}
__device__ __forceinline__ int wswz(int idx) {
  const int row = idx >> 7, f4 = idx & 127;
  return row * WROW + (f4 >> 3) * 36 + (f4 & 7) * 4;
}

// Coherent 16B load (sc1 = device-coherent point; proven pattern).
#define LDG_C(dst, p) \
  asm volatile("global_load_dwordx4 %0, %1, off sc1" : "=v"(dst) : "v"(p))

// ---------------------------------------------------------------------------
// Round-2-proven wait: wave0 polls (lanes 0-31 line a, lanes 32-63 line b),
// then __syncthreads broadcasts. (Round 3's all-wave polling regressed —
// coherent-point line serialization with 8x pollers.)
// ---------------------------------------------------------------------------
__device__ __forceinline__ void stamp_wait(const unsigned* a, int ta,
                                           const unsigned* b, int tb) {
  if (threadIdx.x < 64) {
    const int l = threadIdx.x;
    const unsigned* p = (l < 32) ? (a + l) : (b + (l - 32));
    const int tg = (l < 32) ? ta : tb;
    for (;;) {
      const int sv = (int)__hip_atomic_load(p, __ATOMIC_RELAXED,
                                            __HIP_MEMORY_SCOPE_AGENT);
      if (__all(sv >= tg)) break;
      __builtin_amdgcn_s_sleep(1);
    }
  }
  __syncthreads();
}

// ---------------------------------------------------------------------------
// Kernel 4: persistent recurrence, 128 blocks x 512 threads — round-2
// structure verbatim, with ONE mechanism changed: weights are LDS-RESIDENT
// (staged once before the t-loop). Round 2's VGPR_Count=104 proved w[4][8]
// was never register-resident — it was re-materialized/spilled and
// re-streamed (~256KB/block/step from L2) every timestep, the dominant
// stall. Round 4 proved forcing it into registers explodes into scratch
// spills. LDS is the right home: 32KB (L0) / 64KB (L1) per block, read as
// 2-way-broadcast conflict-free ds_read_b128.
// part reduce buffer aliases h-tile space (L0 -> hst1 region, unused by L0;
// L1 -> hst0 region, with an extra barrier after FMA before part writes).
// Stamp semantics identical to round 2.
// ---------------------------------------------------------------------------
__global__ __launch_bounds__(512, 2) void rnn_persist(
    const float* __restrict__ WT,
    const float* __restrict__ bh0,
    const float* __restrict__ bi1,
    const float* __restrict__ bh1,
    float* __restrict__ outbuf,
    float* __restrict__ ws) {
  extern __shared__ float smem[];

  const int tid = threadIdx.x;
  const int bid = blockIdx.x;
  const int g = bid & 1;
  const int layer = (bid >> 1) & 1;
  const int cb2 = bid >> 2;          // [0,32)
  const int sb = tid >> 8;           // sub-block 0/1
  const int st = tid & 255;
  const int col0 = (cb2 * 2 + sb) * 8;
  const int bbase = g * 16;

  float* hst0 = smem;
  float* hst1 = smem + HT_F;
  float* wldsA = smem + 2 * HT_F;
  float* wldsB = wldsA + WT_F;
  // part aliases: L0 -> hst1 region (L0 never touches hst1); L1 -> hst0
  // region (guarded by an extra barrier after the FMA loop).
  float* part = (layer == 0 ? hst1 : smem) + sb * PART_F;

  float* h0b = ws;
  float* h1b = ws + 32768;
  unsigned* syncp = (unsigned*)(ws + SYNC_OFF);
  unsigned* stampL0 = syncp + g * 32;
  unsigned* stampL1 = syncp + 64 + g * 32;
  const size_t OUT0 = (size_t)NB * LS * HD;

  const int fco = st & 7;
  const int fbo = st >> 3;           // [0,16)
  const int fcol = col0 + fco;
  const int fb = bbase + fbo;

  // -------- one-time weight staging into LDS (plain cached loads) --------
  if (layer == 0) {
    const float* srcW = WT + (size_t)(cb2 * 16) * HD;  // Wh0, cols [cb2*16,+16)
#pragma unroll
    for (int ii = 0; ii < 4; ++ii) {
      const int i = ii * 512 + tid;
      *(f32x4*)&wldsA[wswz(i)] = *(const f32x4*)(srcW + ((size_t)i << 2));
    }
  } else {
    const float* s1 = WT + (size_t)HD * HD + (size_t)(cb2 * 16) * HD;       // Wi1
    const float* s2 = WT + 2 * (size_t)HD * HD + (size_t)(cb2 * 16) * HD;   // Wh1
#pragma unroll
    for (int ii = 0; ii < 4; ++ii) {
      const int i = ii * 512 + tid;
      *(f32x4*)&wldsA[wswz(i)] = *(const f32x4*)(s1 + ((size_t)i << 2));
      *(f32x4*)&wldsB[wswz(i)] = *(const f32x4*)(s2 + ((size_t)i << 2));
    }
  }
  __syncthreads();

  if (layer == 0) {
    const int cg = st & 1;                 // 2 col-groups of 4
    const int ks = (st >> 1) & 15;         // 16 k-slices of 32
    const int bg = st >> 5;                // 8 b-groups of 2
    // LDS weight base for this thread: local col = sb*8 + cg*4 (+ci via WROW)
    const float* wp = wldsA + (size_t)(sb * 8 + cg * 4) * WROW + ks * 36;
    float fbias = 0.f;
    if (st < 128) fbias = bh0[fcol];

    for (int t = 0; t < LS; ++t) {
      // Xi prefetch (plain cached); hazard-free: L1 overwrites out[b,t,:]
      // only after ALL L0 stamps >= t+1.
      float xi = 0.f;
      if (st < 128) xi = outbuf[((size_t)fb * LS + t) * HD + fcol];

      stamp_wait(stampL0, t, stampL1, t - 1);

      {  // stage h0[t-1] -> hst0 (coalesced 16B sc1 loads, swizzled LDS)
        const float* src = h0b + ((t + 1) & 1) * 16384 + bbase * HD;
        f32x4 a, b, c, d;
        LDG_C(a, src + ((0 * 512 + tid) << 2));
        LDG_C(b, src + ((1 * 512 + tid) << 2));
        LDG_C(c, src + ((2 * 512 + tid) << 2));
        LDG_C(d, src + ((3 * 512 + tid) << 2));
        asm volatile("s_waitcnt vmcnt(0)" ::: "memory");
        *(f32x4*)&hst0[swz(0 * 512 + tid)] = a;
        *(f32x4*)&hst0[swz(1 * 512 + tid)] = b;
        *(f32x4*)&hst0[swz(2 * 512 + tid)] = c;
        *(f32x4*)&hst0[swz(3 * 512 + tid)] = d;
      }
      __syncthreads();

      const float* rA = hst0 + (bg * 2) * HROW + ks * 36;
      const float* rB = rA + HROW;
      float acc[4][2] = {};
#pragma unroll
      for (int kk = 0; kk < 8; ++kk) {
        const float4 a4 = *(const float4*)(rA + kk * 4);
        const float4 b4 = *(const float4*)(rB + kk * 4);
#pragma unroll
        for (int ci = 0; ci < 4; ++ci) {
          const float4 wv = *(const float4*)(wp + (size_t)ci * WROW + kk * 4);
          acc[ci][0] = fmaf(wv.x, a4.x, acc[ci][0]);
          acc[ci][0] = fmaf(wv.y, a4.y, acc[ci][0]);
          acc[ci][0] = fmaf(wv.z, a4.z, acc[ci][0]);
          acc[ci][0] = fmaf(wv.w, a4.w, acc[ci][0]);
          acc[ci][1] = fmaf(wv.x, b4.x, acc[ci][1]);
          acc[ci][1] = fmaf(wv.y, b4.y, acc[ci][1]);
          acc[ci][1] = fmaf(wv.z, b4.z, acc[ci][1]);
          acc[ci][1] = fmaf(wv.w, b4.w, acc[ci][1]);
        }
      }
#pragma unroll
      for (int ci = 0; ci < 4; ++ci)
#pragma unroll
        for (int bj = 0; bj < 2; ++bj)
          part[((bg * 2 + bj) * 8 + cg * 4 + ci) * 36 + ks] = acc[ci][bj];
      __syncthreads();
      if (st < 128) {
        const float4* pp = (const float4*)&part[st * 36];
        const float4 p0 = pp[0], p1 = pp[1], p2 = pp[2], p3 = pp[3];
        float sv = (((p0.x + p0.y) + (p0.z + p0.w)) + ((p1.x + p1.y) + (p1.z + p1.w)))
                 + (((p2.x + p2.y) + (p2.z + p2.w)) + ((p3.x + p3.y) + (p3.z + p3.w)))
                 + xi + fbias;
        const float hv = tanhf(sv);
        __hip_atomic_store((unsigned*)(h0b + (t & 1) * 16384 + (size_t)fb * HD + fcol),
                           __builtin_bit_cast(unsigned, hv),
                           __ATOMIC_RELAXED, __HIP_MEMORY_SCOPE_AGENT);
        if (t == LS - 1) outbuf[OUT0 + (size_t)fb * HD + fcol] = hv;  // h_final L0
      }
      // __syncthreads: every wave drains vmcnt(0) (h sc1 stores at the
      // coherent point) before any wave reaches the stamp store below.
      __syncthreads();
      if (tid == 0)
        __hip_atomic_store(stampL0 + cb2, (unsigned)(t + 1),
                           __ATOMIC_RELAXED, __HIP_MEMORY_SCOPE_AGENT);
    }
  } else {
    const int m = st >> 7;                 // 0 = Wi1 (reads h0), 1 = Wh1 (reads h1)
    const int r = st & 127;
    const int cg = r & 1;
    const int ks = (r >> 1) & 15;
    const int bg = r >> 5;                 // 4 b-groups of 4
    const float* wp = (m == 0 ? wldsA : wldsB)
                    + (size_t)(sb * 8 + cg * 4) * WROW + ks * 36;
    float fbias = 0.f;
    if (st < 128) fbias = bi1[fcol] + bh1[fcol];

    for (int t = 0; t < LS; ++t) {
      stamp_wait(stampL0, t + 1, stampL1, t);

      {  // stage h0[t] -> hst0 and h1[t-1] -> hst1
        const float* s0 = h0b + (t & 1) * 16384 + bbase * HD;
        const float* s1 = h1b + ((t + 1) & 1) * 16384 + bbase * HD;
        f32x4 a, b, c, d, e, f, g2, h;
        LDG_C(a, s0 + ((0 * 512 + tid) << 2));
        LDG_C(b, s0 + ((1 * 512 + tid) << 2));
        LDG_C(c, s0 + ((2 * 512 + tid) << 2));
        LDG_C(d, s0 + ((3 * 512 + tid) << 2));
        LDG_C(e, s1 + ((0 * 512 + tid) << 2));
        LDG_C(f, s1 + ((1 * 512 + tid) << 2));
        LDG_C(g2, s1 + ((2 * 512 + tid) << 2));
        LDG_C(h, s1 + ((3 * 512 + tid) << 2));
        asm volatile("s_waitcnt vmcnt(0)" ::: "memory");
        *(f32x4*)&hst0[swz(0 * 512 + tid)] = a;
        *(f32x4*)&hst0[swz(1 * 512 + tid)] = b;
        *(f32x4*)&hst0[swz(2 * 512 + tid)] = c;
        *(f32x4*)&hst0[swz(3 * 512 + tid)] = d;
        *(f32x4*)&hst1[swz(0 * 512 + tid)] = e;
        *(f32x4*)&hst1[swz(1 * 512 + tid)] = f;
        *(f32x4*)&hst1[swz(2 * 512 + tid)] = g2;
        *(f32x4*)&hst1[swz(3 * 512 + tid)] = h;
      }
      __syncthreads();

      const float* hbase = (m == 0) ? hst0 : hst1;
      float acc[4][4] = {};
#pragma unroll
      for (int bj = 0; bj < 4; ++bj) {
        const float* hr = hbase + (bg * 4 + bj) * HROW + ks * 36;
#pragma unroll
        for (int kk = 0; kk < 8; ++kk) {
          const float4 h4 = *(const float4*)(hr + kk * 4);
#pragma unroll
          for (int ci = 0; ci < 4; ++ci) {
            const float4 wv = *(const float4*)(wp + (size_t)ci * WROW + kk * 4);
            acc[ci][bj] = fmaf(wv.x, h4.x, acc[ci][bj]);
            acc[ci][bj] = fmaf(wv.y, h4.y, acc[ci][bj]);
            acc[ci][bj] = fmaf(wv.z, h4.z, acc[ci][bj]);
            acc[ci][bj] = fmaf(wv.w, h4.w, acc[ci][bj]);
          }
        }
      }
      // part aliases hst0 — all FMA reads of hst0/hst1 must complete first.
      __syncthreads();
#pragma unroll
      for (int ci = 0; ci < 4; ++ci)
#pragma unroll
        for (int bj = 0; bj < 4; ++bj)
          part[((bg * 4 + bj) * 8 + cg * 4 + ci) * 36 + m * 16 + ks] = acc[ci][bj];
      __syncthreads();
      if (st < 128) {
        const float4* pp = (const float4*)&part[st * 36];
        float sv = fbias;
#pragma unroll
        for (int j = 0; j < 8; ++j) {
          const float4 p = pp[j];
          sv += ((p.x + p.y) + (p.z + p.w));
        }
        const float hv = tanhf(sv);
        __hip_atomic_store((unsigned*)(h1b + (t & 1) * 16384 + (size_t)fb * HD + fcol),
                           __builtin_bit_cast(unsigned, hv),
                           __ATOMIC_RELAXED, __HIP_MEMORY_SCOPE_AGENT);
        outbuf[((size_t)fb * LS + t) * HD + fcol] = hv;
        if (t == LS - 1) outbuf[OUT0 + NB * HD + (size_t)fb * HD + fcol] = hv;  // h_final L1
      }
      __syncthreads();  // drains the atomic h1 stores (compiler-known)
      if (tid == 0)
        __hip_atomic_store(stampL1 + cb2, (unsigned)(t + 1),
                           __ATOMIC_RELAXED, __HIP_MEMORY_SCOPE_AGENT);
    }
  }
}

// ---------------------------------------------------------------------------
// ws layout (floats): [0,65536) h dbufs; [65536,65536+786432) WT;
// [SYNC_OFF, SYNC_OFF+256) per-block progress stamps (u32, 128 used).
// ---------------------------------------------------------------------------
extern "C" void kernel_launch(void* const* d_in, const int* in_sizes, int n_in,
                              void* d_out, int out_size, void* d_ws, size_t ws_size,
                              hipStream_t stream) {
  const float* x  = (const float*)d_in[0];
  const float* h0 = (const float*)d_in[1];
  const float* Wi = (const float*)d_in[2];
  const float* bi = (const float*)d_in[3];
  const float* Wh = (const float*)d_in[4];
  const float* bh = (const float*)d_in[5];
  float* out = (float*)d_out;
  float* ws  = (float*)d_ws;

  const float* Wi0 = Wi;
  const float* Wi1 = Wi + (size_t)HD * HD;
  const float* bi0 = bi;
  const float* bi1 = bi + HD;
  const float* Wh0 = Wh;
  const float* Wh1 = Wh + (size_t)HD * HD;
  const float* bh0 = bh;
  const float* bh1 = bh + HD;

  const float* WT = ws + 65536;

  hipFuncSetAttribute((const void*)rnn_persist,
                      hipFuncAttributeMaxDynamicSharedMemorySize, SMEM_BYTES);

  xi_gemm<<<dim3(8, 1024), 256, 0, stream>>>(x, Wi0, bi0, out);
  transpose_w<<<dim3(2, 512, 3), 256, 0, stream>>>(Wh0, Wi1, Wh1, ws + 65536);
  init_h<<<128, 256, 0, stream>>>(h0, ws);

  void* kargs[] = {(void*)&WT, (void*)&bh0, (void*)&bi1, (void*)&bh1,
                   (void*)&out, (void*)&ws};
  hipLaunchCooperativeKernel((const void*)rnn_persist, dim3(128), dim3(512),
                             kargs, SMEM_BYTES, stream);
}